// Round 11
// baseline (212.533 us; speedup 1.0000x reference)
//
#include <hip/hip_runtime.h>

#define B_   2
#define SQ_  2048
#define SK_  512
#define HID_ 1024
#define NH_  16
#define HD_  64

typedef __bf16 bf16x8 __attribute__((ext_vector_type(8)));
typedef float  f32x4  __attribute__((ext_vector_type(4)));

__device__ __forceinline__ unsigned short f2bf(float f) {
    unsigned u = __builtin_bit_cast(unsigned, f);
    u += 0x7fffu + ((u >> 16) & 1u);   // round-to-nearest-even
    return (unsigned short)(u >> 16);
}

// async global->LDS, 16B per lane, lands at lds_base + lane*16
__device__ __forceinline__ void gll16(const unsigned short* g, unsigned short* l) {
    __builtin_amdgcn_global_load_lds(
        (const __attribute__((address_space(1))) unsigned int*)(const void*)g,
        (__attribute__((address_space(3))) unsigned int*)(void*)l,
        16, 0, 0);
}

// ---------------- fused fp32 -> bf16 conversion (all 5 tensors) ----------------
__global__ __launch_bounds__(256) void cvt_all(const float* __restrict__ hs,
                                               const float* __restrict__ enc,
                                               const float* __restrict__ wq,
                                               const float* __restrict__ wk,
                                               const float* __restrict__ wv,
                                               unsigned short* __restrict__ hb,
                                               unsigned short* __restrict__ eb,
                                               unsigned short* __restrict__ wqb,
                                               unsigned short* __restrict__ wkb,
                                               unsigned short* __restrict__ wvb) {
    size_t i = ((size_t)blockIdx.x * 256 + threadIdx.x) * 4;
    const float* s; unsigned short* d; size_t off;
    if (i < 4194304)      { s = hs;  d = hb;  off = i; }
    else if (i < 5242880) { s = enc; d = eb;  off = i - 4194304; }
    else if (i < 6291456) { s = wq;  d = wqb; off = i - 5242880; }
    else if (i < 7340032) { s = wk;  d = wkb; off = i - 6291456; }
    else                  { s = wv;  d = wvb; off = i - 7340032; }
    float4 v = *reinterpret_cast<const float4*>(s + off);
    ushort4 o;
    o.x = f2bf(v.x); o.y = f2bf(v.y); o.z = f2bf(v.z); o.w = f2bf(v.w);
    *reinterpret_cast<ushort4*>(d + off) = o;
}

// ---------------- fused QKV NT GEMM (round-3 best: BK=64, dbuf, grid 768) ----------------
// Measured round 6: compute-only ~11.4 us -> near floor. Frozen.
__global__ __launch_bounds__(256, 3) void gemm_qkv(const unsigned short* __restrict__ hb,
                                                   const unsigned short* __restrict__ eb,
                                                   const unsigned short* __restrict__ wq,
                                                   const unsigned short* __restrict__ wk,
                                                   const unsigned short* __restrict__ wv,
                                                   unsigned short* __restrict__ qo,
                                                   unsigned short* __restrict__ ko,
                                                   unsigned short* __restrict__ vo) {
    __shared__ unsigned short as[2][64 * 64];     // [buf][row][64 k], 128B rows, swizzled chunks
    __shared__ unsigned short bs[2][128 * 64];

    int bid = blockIdx.x;
    bid = (bid & 7) * 96 + (bid >> 3);        // XCD swizzle: 12 ms-superblocks per XCD
    int nb = bid & 7, ms = bid >> 3;
    const unsigned short* Ab; const unsigned short* Wb;
    int mrow, mode;
    if (ms < 64)      { mode = 0; Ab = hb; Wb = wq; mrow = ms * 64; }
    else if (ms < 80) { mode = 1; Ab = eb; Wb = wk; mrow = (ms - 64) * 64; }
    else              { mode = 2; Ab = eb; Wb = wv; mrow = (ms - 80) * 64; }
    int n0 = nb * 128;

    int tid = threadIdx.x, lane = tid & 63, w = tid >> 6;
    int quad = lane >> 4, lc = lane & 15;

    // loader mapping for 128B rows: row-in-8 = lane>>3, slot = lane&7,
    // fetched logical chunk = slot ^ (lane>>3)
    int lr  = lane >> 3;
    int chg = (lane & 7) ^ lr;

    f32x4 zero4 = {0.f, 0.f, 0.f, 0.f};
    f32x4 acc[4][2];
#pragma unroll
    for (int i = 0; i < 4; i++) { acc[i][0] = zero4; acc[i][1] = zero4; }

    int rsw = lc & 7;   // reader swizzle: slot = chunk ^ (row&7)

    // prologue: stage k-tile 0 into buf 0
#pragma unroll
    for (int j = 0; j < 2; j++) {
        int c = w * 2 + j;
        gll16(Ab + (size_t)(mrow + c * 8 + lr) * 1024 + chg * 8, &as[0][(c * 8) * 64]);
    }
#pragma unroll
    for (int j = 0; j < 4; j++) {
        int c = w * 4 + j;
        gll16(Wb + (size_t)(n0 + c * 8 + lr) * 1024 + chg * 8, &bs[0][(c * 8) * 64]);
    }
    __syncthreads();

#pragma unroll 2
    for (int it = 0; it < 16; ++it) {
        int cur = it & 1;
        if (it < 15) {
            int k0n = (it + 1) * 64;
#pragma unroll
            for (int j = 0; j < 2; j++) {
                int c = w * 2 + j;
                gll16(Ab + (size_t)(mrow + c * 8 + lr) * 1024 + k0n + chg * 8,
                      &as[cur ^ 1][(c * 8) * 64]);
            }
#pragma unroll
            for (int j = 0; j < 4; j++) {
                int c = w * 4 + j;
                gll16(Wb + (size_t)(n0 + c * 8 + lr) * 1024 + k0n + chg * 8,
                      &bs[cur ^ 1][(c * 8) * 64]);
            }
        }
#pragma unroll
        for (int kk = 0; kk < 2; kk++) {
            bf16x8 af[4], bfr[2];
#pragma unroll
            for (int mt = 0; mt < 4; mt++)
                af[mt] = *reinterpret_cast<const bf16x8*>(
                    &as[cur][(mt * 16 + lc) * 64 + ((kk * 4 + quad) ^ rsw) * 8]);
#pragma unroll
            for (int nt = 0; nt < 2; nt++)
                bfr[nt] = *reinterpret_cast<const bf16x8*>(
                    &bs[cur][(w * 32 + nt * 16 + lc) * 64 + ((kk * 4 + quad) ^ rsw) * 8]);
#pragma unroll
            for (int mt = 0; mt < 4; mt++)
#pragma unroll
                for (int nt = 0; nt < 2; nt++)
                    acc[mt][nt] = __builtin_amdgcn_mfma_f32_16x16x32_bf16(af[mt], bfr[nt], acc[mt][nt], 0, 0, 0);
        }
        __syncthreads();
    }

#pragma unroll
    for (int mt = 0; mt < 4; mt++) {
#pragma unroll
        for (int nt = 0; nt < 2; nt++) {
            int n = n0 + w * 32 + nt * 16 + lc;
            int h = n >> 6, d = n & 63;
#pragma unroll
            for (int r = 0; r < 4; r++) {
                int M = mrow + mt * 16 + quad * 4 + r;
                unsigned short val = f2bf(acc[mt][nt][r]);
                if (mode == 0) {
                    int b = M >> 11, s = M & 2047;
                    qo[(((size_t)(b * NH_ + h)) * SQ_ + s) * HD_ + d] = val;
                } else if (mode == 1) {
                    int b = M >> 9, s = M & 511;
                    ko[(((size_t)(b * NH_ + h)) * SK_ + s) * HD_ + d] = val;
                } else {
                    int b = M >> 9, s = M & 511;
                    vo[(((size_t)(b * NH_ + h)) * HD_ + d) * SK_ + s] = val;
                }
            }
        }
    }
}

// ---------------- fused attention (flash, occ 4, counted-vmcnt pipeline) ----------------
// r10 diagnosis: __syncthreads' vmcnt(0) drained the K-prefetch AND the score
// stores every tile -> compute and HBM writes serialized (44us ~= 20 compute +
// 23 writes). This round = T3/T4 template: V dbuf so ALL prefetches (K x2 via
// qs/ks alternation, V x2) issue at tile top; ONE raw s_barrier per tile with
// s_waitcnt vmcnt(4) — retires the 4 prefetches (oldest), leaves the 4 score
// stores (newest) permanently in flight. ps halved (pack/PV per 32-col half)
// to fit V dbuf in 38.5KB -> occupancy 4 kept.
#define PSH 36   // ps half stride (shorts): 72B rows, 2-way conflict on b128 reads

__global__ __launch_bounds__(256, 4) void attn_kernel(const unsigned short* __restrict__ qh,
                                                      const unsigned short* __restrict__ kh,
                                                      const unsigned short* __restrict__ vh,
                                                      const int* __restrict__ maskp,
                                                      float* __restrict__ octx,
                                                      float* __restrict__ oscores) {
    __shared__ unsigned short qs[64 * 64];     // Q tile; K buffer #1 after qf read
    __shared__ unsigned short ks[64 * 64];     // K buffer #0
    __shared__ unsigned short vts[2][64 * 64]; // V^T [d][s_local] double buffer
    __shared__ unsigned short ps[64 * PSH];    // P half-chunk (32 cols), wave-private rows
    __shared__ float lm[SK_];

    int bid = blockIdx.x;
    bid = (bid & 7) * 128 + (bid >> 3);        // XCD swizzle: 4 whole heads per XCD
    int qt = bid & 31;
    int h  = (bid >> 5) & 15;
    int b  = bid >> 9;

    int tid = threadIdx.x, lane = tid & 63, w = tid >> 6;
    int quad = lane >> 4, lc = lane & 15;
    int wrow = w * 16;

    const unsigned short* qp = qh + ((size_t)(b * NH_ + h) * SQ_ + qt * 64) * HD_;
    const unsigned short* kp = kh + ((size_t)(b * NH_ + h) * SK_) * HD_;
    const unsigned short* vp = vh + ((size_t)(b * NH_ + h) * HD_) * SK_;  // [d][s]

    // loader mapping for 128B-row tiles: row-in-8 = lane>>3, slot = lane&7,
    // fetched logical chunk = slot ^ (lane>>3)
    int lr  = lane >> 3;
    int chg = (lane & 7) ^ lr;

    // prologue: stage q + K0 + V0 + mask; full __syncthreads (once, safe)
#pragma unroll
    for (int j = 0; j < 2; j++) {
        int c = w * 2 + j;
        gll16(qp + (c * 8 + lr) * 64 + chg * 8, &qs[c * 512]);
        gll16(kp + (c * 8 + lr) * 64 + chg * 8, &ks[c * 512]);
        gll16(vp + (size_t)(c * 8 + lr) * SK_ + chg * 8, &vts[0][c * 512]);
    }
    // mask table in exp2 domain: valid -> -16*log2e, masked -> -3e38 (exp2 -> 0)
#pragma unroll
    for (int i = 0; i < 2; i++) {
        int c = tid + i * 256;
        lm[c] = maskp[b * SK_ + c] ? -23.0831227f : -3.0e38f;
    }
    __syncthreads();

    int rsw = lc & 7;   // reader swizzle for 8-chunk rows
    bf16x8 qf[2];
#pragma unroll
    for (int hf = 0; hf < 2; hf++)
        qf[hf] = *reinterpret_cast<const bf16x8*>(&qs[(wrow + lc) * 64 + ((quad + hf * 4) ^ rsw) * 8]);
    __syncthreads();   // all qf reads retired -> qs free for K reuse

    f32x4 zero4 = {0.f, 0.f, 0.f, 0.f};
    f32x4 cacc[4];
#pragma unroll
    for (int ct = 0; ct < 4; ct++) cacc[ct] = zero4;
    float lsum = 0.0f;

    float* srowp = oscores + ((size_t)(b * NH_ + h) * SQ_ + qt * 64 + wrow + lc) * SK_;

    for (int kt = 0; kt < 8; kt++) {
        const unsigned short* kcur = (kt & 1) ? qs : ks;
        const unsigned short* vcur = vts[kt & 1];

        // ---- ALL prefetches at tile top (4 gll16, oldest vmem of this tile) ----
        if (kt < 7) {
            unsigned short* knxt = (kt & 1) ? ks : qs;
            unsigned short* vnxt = vts[(kt + 1) & 1];
#pragma unroll
            for (int j = 0; j < 2; j++) {
                int c = w * 2 + j;
                gll16(kp + ((kt + 1) * 64 + c * 8 + lr) * 64 + chg * 8, &knxt[c * 512]);
                gll16(vp + (size_t)(c * 8 + lr) * SK_ + (kt + 1) * 64 + chg * 8, &vnxt[c * 512]);
            }
            // pin issue order: prefetches must stay OLDER than the score stores
            // (the vmcnt(4) count below depends on it)
            __builtin_amdgcn_sched_barrier(0);
        }

        // ---- S^T tile = (K q^T): lane holds q-row wrow+lc, k-cols (kt*4+tl)*16+quad*4..+3
        f32x4 s[4];
#pragma unroll
        for (int tl = 0; tl < 4; tl++) s[tl] = zero4;
        __builtin_amdgcn_s_setprio(1);
#pragma unroll
        for (int tl = 0; tl < 4; tl++) {
#pragma unroll
            for (int hf = 0; hf < 2; hf++) {
                bf16x8 kf = *reinterpret_cast<const bf16x8*>(
                    &kcur[(tl * 16 + lc) * 64 + ((quad + hf * 4) ^ rsw) * 8]);
                s[tl] = __builtin_amdgcn_mfma_f32_16x16x32_bf16(kf, qf[hf], s[tl], 0, 0, 0);
            }
        }
        __builtin_amdgcn_s_setprio(0);

        // ---- scale + coalesced score stores (4 dwordx4; never drained — retire async)
#pragma unroll
        for (int tl = 0; tl < 4; tl++) {
            f32x4 sc = s[tl] * 0.125f;
            *reinterpret_cast<f32x4*>(&srowp[(kt * 4 + tl) * 16 + quad * 4]) = sc;
        }

        // ---- two 32-col halves: exp2 + pack -> ps, then PV MFMA ----
#pragma unroll
        for (int ks2 = 0; ks2 < 2; ks2++) {
#pragma unroll
            for (int u = 0; u < 2; u++) {
                int t = ks2 * 2 + u;
                float4 mv = *reinterpret_cast<const float4*>(&lm[(kt * 4 + t) * 16 + quad * 4]);
                float e0 = __builtin_amdgcn_exp2f(fmaf(s[t][0], 0.1803369f, mv.x));
                float e1 = __builtin_amdgcn_exp2f(fmaf(s[t][1], 0.1803369f, mv.y));
                float e2 = __builtin_amdgcn_exp2f(fmaf(s[t][2], 0.1803369f, mv.z));
                float e3 = __builtin_amdgcn_exp2f(fmaf(s[t][3], 0.1803369f, mv.w));
                lsum += (e0 + e1) + (e2 + e3);
                unsigned plo, phi;
                asm("v_cvt_pk_bf16_f32 %0, %1, %2" : "=v"(plo) : "v"(e0), "v"(e1));
                asm("v_cvt_pk_bf16_f32 %0, %1, %2" : "=v"(phi) : "v"(e2), "v"(e3));
                uint2 pk; pk.x = plo; pk.y = phi;
                *reinterpret_cast<uint2*>(&ps[(wrow + lc) * PSH + u * 16 + quad * 4]) = pk;
            }
            // wave-private rows: same-wave LDS ordering makes write->read safe
            bf16x8 af = *reinterpret_cast<const bf16x8*>(&ps[(wrow + lc) * PSH + quad * 8]);
            __builtin_amdgcn_s_setprio(1);
#pragma unroll
            for (int ct = 0; ct < 4; ct++) {
                bf16x8 bv = *reinterpret_cast<const bf16x8*>(
                    &vcur[(ct * 16 + lc) * 64 + ((quad + ks2 * 4) ^ rsw) * 8]);
                cacc[ct] = __builtin_amdgcn_mfma_f32_16x16x32_bf16(af, bv, cacc[ct], 0, 0, 0);
            }
            __builtin_amdgcn_s_setprio(0);
        }

        // ---- counted-vmcnt barrier: retire the 4 prefetches (oldest), leave the
        // 4 score stores (newest) in flight. Raw s_barrier: no auto vmcnt(0) drain.
        if (kt < 7) {
            asm volatile("s_waitcnt vmcnt(4)" ::: "memory");
            __builtin_amdgcn_s_barrier();
            __builtin_amdgcn_sched_barrier(0);   // fence: no LDS reads hoisted above
        }
    }

    // ---- epilogue: full-row sums, normalize, store context
    lsum += __shfl_xor(lsum, 16);
    lsum += __shfl_xor(lsum, 32);
    // cacc rows are q-in-16 = quad*4+r; lane (quad*4+r) holds that row's sum
    float linv[4];
#pragma unroll
    for (int r = 0; r < 4; r++) linv[r] = 1.0f / __shfl(lsum, quad * 4 + r);
#pragma unroll
    for (int ct = 0; ct < 4; ct++) {
        int d = ct * 16 + lc;
#pragma unroll
        for (int r = 0; r < 4; r++) {
            int s = qt * 64 + wrow + quad * 4 + r;
            octx[((size_t)b * SQ_ + s) * HID_ + h * HD_ + d] = cacc[ct][r] * linv[r];
        }
    }
}

// ---------------- launch ----------------
extern "C" void kernel_launch(void* const* d_in, const int* in_sizes, int n_in,
                              void* d_out, int out_size, void* d_ws, size_t ws_size,
                              hipStream_t stream) {
    const float* hs   = (const float*)d_in[0];
    const float* enc  = (const float*)d_in[1];
    const int*   mask = (const int*)d_in[2];
    const float* Wq   = (const float*)d_in[3];
    const float* Wk   = (const float*)d_in[4];
    const float* Wv   = (const float*)d_in[5];
    float* out = (float*)d_out;

    unsigned short* hb  = (unsigned short*)d_ws;      // hidden bf16   (4194304)
    unsigned short* eb  = hb  + 4194304;              // encoder bf16  (1048576)
    unsigned short* wqb = eb  + 1048576;
    unsigned short* wkb = wqb + 1048576;
    unsigned short* wvb = wkb + 1048576;
    unsigned short* qhp = wvb + 1048576;              // q [b,h,s,d]   (4194304)
    unsigned short* khp = qhp + 4194304;              // k [b,h,s,d]   (1048576)
    unsigned short* vhp = khp + 1048576;              // v [b,h,d,s]   (1048576)

    cvt_all<<<8192, 256, 0, stream>>>(hs, enc, Wq, Wk, Wv, hb, eb, wqb, wkb, wvb);
    gemm_qkv<<<768, 256, 0, stream>>>(hb, eb, wqb, wkb, wvb, qhp, khp, vhp);
    attn_kernel<<<1024, 256, 0, stream>>>(qhp, khp, vhp, mask, out, out + 4194304);
}